// Round 1
// baseline (53.115 us; speedup 1.0000x reference)
//
#include <hip/hip_runtime.h>
#include <math.h>

#define POOL 7
#define CCH 256   // channels
#define CANON 224.0f

__device__ __forceinline__ float4 f4_blend(float4 a, float4 b, float w) {
    // a + (b - a) * w, matching reference order
    float4 r;
    r.x = a.x + (b.x - a.x) * w;
    r.y = a.y + (b.y - a.y) * w;
    r.z = a.z + (b.z - a.z) * w;
    r.w = a.w + (b.w - a.w) * w;
    return r;
}

__global__ __launch_bounds__(256) void roi_align_kernel(
    const float* __restrict__ rois,   // [B,N,4] (y1,x1,y2,x2) normalized
    const float* __restrict__ metas,  // [B,11]
    const float* __restrict__ fm2,    // [B,256,256,256]
    const float* __restrict__ fm3,    // [B,128,128,256]
    const float* __restrict__ fm4,    // [B,64,64,256]
    const float* __restrict__ fm5,    // [B,32,32,256]
    float* __restrict__ out,          // [B,N,7,7,256]
    int B, int N)
{
    const int idx = blockIdx.x;            // b*N + n
    if (idx >= B * N) return;
    const int b = idx / N;

    // ---- ROI level selection (replicates reference f32 math) ----
    const float* box = rois + (size_t)idx * 4;
    const float y1 = box[0], x1 = box[1], y2 = box[2], x2 = box[3];
    const float h = y2 - y1;
    const float w = x2 - x1;
    const float pad_h = metas[b * 11 + 7];
    const float pad_w = metas[b * 11 + 8];
    const float area = pad_h * pad_w;
    // roi_level = log(sqrt(h*w) / (224/sqrt(area))) / log(2)
    const float lvlf = logf(sqrtf(h * w) / (CANON / sqrtf(area))) / logf(2.0f);
    int lvl = 4 + (int)rintf(lvlf);        // rintf = round-half-even, matches jnp.round
    lvl = lvl < 2 ? 2 : (lvl > 5 ? 5 : lvl);

    const float* fm;
    int H, W;
    if (lvl == 2)      { fm = fm2; H = 256; W = 256; }
    else if (lvl == 3) { fm = fm3; H = 128; W = 128; }
    else if (lvl == 4) { fm = fm4; H = 64;  W = 64;  }
    else               { fm = fm5; H = 32;  W = 32;  }
    const float* img = fm + (size_t)b * H * W * CCH;

    const int tid  = threadIdx.x;
    const int wave = tid >> 6;   // 0..3
    const int lane = tid & 63;   // 64 lanes, each owns 4 channels (float4)

    float4* outp = (float4*)(out + (size_t)idx * (POOL * POOL * CCH));

    const float Hm1 = (float)(H - 1);
    const float Wm1 = (float)(W - 1);

    for (int p = wave; p < POOL * POOL; p += 4) {
        const int i = p / POOL;
        const int j = p % POOL;
        // ys = (y1 + (i/6)*(y2-y1)) * (H-1)   (same op order as reference)
        const float ii = (float)i / 6.0f;
        const float jj = (float)j / 6.0f;
        const float ys = (y1 + ii * h) * Hm1;
        const float xs = (x1 + jj * w) * Wm1;

        const float y0f = floorf(ys);
        const float x0f = floorf(xs);
        const float wy = ys - y0f;
        const float wx = xs - x0f;

        int y0 = (int)y0f; y0 = y0 < 0 ? 0 : (y0 > H - 1 ? H - 1 : y0);
        int x0 = (int)x0f; x0 = x0 < 0 ? 0 : (x0 > W - 1 ? W - 1 : x0);
        int y1i = y0 + 1;  y1i = y1i > H - 1 ? H - 1 : y1i;
        int x1i = x0 + 1;  x1i = x1i > W - 1 ? W - 1 : x1i;

        const float4* tl = (const float4*)(img + ((size_t)(y0  * W + x0 )) * CCH) + lane;
        const float4* tr = (const float4*)(img + ((size_t)(y0  * W + x1i)) * CCH) + lane;
        const float4* bl = (const float4*)(img + ((size_t)(y1i * W + x0 )) * CCH) + lane;
        const float4* br = (const float4*)(img + ((size_t)(y1i * W + x1i)) * CCH) + lane;

        const float4 vtl = *tl;
        const float4 vtr = *tr;
        const float4 vbl = *bl;
        const float4 vbr = *br;

        const float4 top = f4_blend(vtl, vtr, wx);
        const float4 bot = f4_blend(vbl, vbr, wx);
        const float4 res = f4_blend(top, bot, wy);

        outp[p * 64 + lane] = res;
    }
}

extern "C" void kernel_launch(void* const* d_in, const int* in_sizes, int n_in,
                              void* d_out, int out_size, void* d_ws, size_t ws_size,
                              hipStream_t stream) {
    const float* rois  = (const float*)d_in[0];
    const float* metas = (const float*)d_in[1];
    const float* fm2   = (const float*)d_in[2];
    const float* fm3   = (const float*)d_in[3];
    const float* fm4   = (const float*)d_in[4];
    const float* fm5   = (const float*)d_in[5];
    float* out = (float*)d_out;

    const int B = in_sizes[1] / 11;          // img_metas: [B,11]
    const int N = in_sizes[0] / (4 * B);     // rois: [B,N,4]

    dim3 grid(B * N);
    dim3 block(256);
    roi_align_kernel<<<grid, block, 0, stream>>>(rois, metas, fm2, fm3, fm4, fm5,
                                                 out, B, N);
}

// Round 3
// 50.062 us; speedup vs baseline: 1.0610x; 1.0610x over previous
//
#include <hip/hip_runtime.h>
#include <math.h>

#define POOL 7
#define CCH 256   // channels
#define CANON 224.0f

typedef float nfloat4 __attribute__((ext_vector_type(4)));  // native vec for nontemporal builtin

__device__ __forceinline__ nfloat4 f4_blend(nfloat4 a, nfloat4 b, float w) {
    return a + (b - a) * w;   // elementwise, matches reference op order
}

__global__ __launch_bounds__(256) void roi_align_kernel(
    const float* __restrict__ rois,   // [B,N,4] (y1,x1,y2,x2) normalized
    const float* __restrict__ metas,  // [B,11]
    const float* __restrict__ fm2,    // [B,256,256,256]
    const float* __restrict__ fm3,    // [B,128,128,256]
    const float* __restrict__ fm4,    // [B,64,64,256]
    const float* __restrict__ fm5,    // [B,32,32,256]
    float* __restrict__ out,          // [B,N,7,7,256]
    int B, int N)
{
    const int idx = blockIdx.x;            // b*N + n
    if (idx >= B * N) return;
    const int b = idx / N;

    // ---- ROI level selection (replicates reference f32 math) ----
    const float* box = rois + (size_t)idx * 4;
    const float y1 = box[0], x1 = box[1], y2 = box[2], x2 = box[3];
    const float h = y2 - y1;
    const float w = x2 - x1;
    const float pad_h = metas[b * 11 + 7];
    const float pad_w = metas[b * 11 + 8];
    const float area = pad_h * pad_w;
    const float lvlf = logf(sqrtf(h * w) / (CANON / sqrtf(area))) / logf(2.0f);
    int lvl = 4 + (int)rintf(lvlf);        // rintf = round-half-even, matches jnp.round
    lvl = lvl < 2 ? 2 : (lvl > 5 ? 5 : lvl);

    const float* fm;
    int H, W;
    if (lvl == 2)      { fm = fm2; H = 256; W = 256; }
    else if (lvl == 3) { fm = fm3; H = 128; W = 128; }
    else if (lvl == 4) { fm = fm4; H = 64;  W = 64;  }
    else               { fm = fm5; H = 32;  W = 32;  }
    const float* img = fm + (size_t)b * H * W * CCH;

    const int tid  = threadIdx.x;
    const int wave = tid >> 6;   // 0..3
    const int lane = tid & 63;   // 64 lanes, each owns 4 channels (float4)

    nfloat4* outp = (nfloat4*)(out + (size_t)idx * (POOL * POOL * CCH));

    const float Hm1 = (float)(H - 1);
    const float Wm1 = (float)(W - 1);

    // 49 points padded to 52: all 4 waves run 13 iterations (constant trip
    // count -> unrollable). p>48 clamps to 48; the duplicate stores write
    // identical data (benign).
#pragma unroll 4
    for (int it = 0; it < 13; ++it) {
        int p = wave + it * 4;
        p = p > 48 ? 48 : p;
        const int i = p / POOL;
        const int j = p % POOL;
        const float ii = (float)i / 6.0f;
        const float jj = (float)j / 6.0f;
        const float ys = (y1 + ii * h) * Hm1;
        const float xs = (x1 + jj * w) * Wm1;

        const float y0f = floorf(ys);
        const float x0f = floorf(xs);
        const float wy = ys - y0f;
        const float wx = xs - x0f;

        int y0 = (int)y0f; y0 = y0 < 0 ? 0 : (y0 > H - 1 ? H - 1 : y0);
        int x0 = (int)x0f; x0 = x0 < 0 ? 0 : (x0 > W - 1 ? W - 1 : x0);
        int y1i = y0 + 1;  y1i = y1i > H - 1 ? H - 1 : y1i;
        int x1i = x0 + 1;  x1i = x1i > W - 1 ? W - 1 : x1i;

        const nfloat4* tl = (const nfloat4*)(img + ((size_t)(y0  * W + x0 )) * CCH) + lane;
        const nfloat4* tr = (const nfloat4*)(img + ((size_t)(y0  * W + x1i)) * CCH) + lane;
        const nfloat4* bl = (const nfloat4*)(img + ((size_t)(y1i * W + x0 )) * CCH) + lane;
        const nfloat4* br = (const nfloat4*)(img + ((size_t)(y1i * W + x1i)) * CCH) + lane;

        const nfloat4 vtl = *tl;
        const nfloat4 vtr = *tr;
        const nfloat4 vbl = *bl;
        const nfloat4 vbr = *br;

        const nfloat4 top = f4_blend(vtl, vtr, wx);
        const nfloat4 bot = f4_blend(vbl, vbr, wx);
        const nfloat4 res = f4_blend(top, bot, wy);

        // Streaming output: bypass caches so fm tap reads keep L2/L3.
        __builtin_nontemporal_store(res, &outp[p * 64 + lane]);
    }
}

extern "C" void kernel_launch(void* const* d_in, const int* in_sizes, int n_in,
                              void* d_out, int out_size, void* d_ws, size_t ws_size,
                              hipStream_t stream) {
    const float* rois  = (const float*)d_in[0];
    const float* metas = (const float*)d_in[1];
    const float* fm2   = (const float*)d_in[2];
    const float* fm3   = (const float*)d_in[3];
    const float* fm4   = (const float*)d_in[4];
    const float* fm5   = (const float*)d_in[5];
    float* out = (float*)d_out;

    const int B = in_sizes[1] / 11;          // img_metas: [B,11]
    const int N = in_sizes[0] / (4 * B);     // rois: [B,N,4]

    dim3 grid(B * N);
    dim3 block(256);
    roi_align_kernel<<<grid, block, 0, stream>>>(rois, metas, fm2, fm3, fm4, fm5,
                                                 out, B, N);
}